// Round 1
// baseline (4498.844 us; speedup 1.0000x reference)
//
#include <hip/hip_runtime.h>
#include <hip/hip_bf16.h>
#include <stdint.h>

#define B_DIM 128
#define T_DIM 1024
#define NX 256
#define NH 512
#define NY 256
#define Y_ELEMS (B_DIM * T_DIM * NY)   /* 33,554,432 fp32 slots in d_out */
#define HS_ELEMS (B_DIM * T_DIM * NH)  /* 67,108,864 */

typedef __attribute__((ext_vector_type(8))) short short8;
typedef __attribute__((ext_vector_type(4))) float floatx4;
typedef __attribute__((ext_vector_type(4))) unsigned short ushort4v;

static __device__ __forceinline__ float bf16_to_f32(unsigned short u) {
    union { unsigned int i; float f; } v;
    v.i = ((unsigned int)u) << 16;
    return v.f;
}
static __device__ __forceinline__ unsigned short f32_to_bf16(float f) {
    union { float f; unsigned int i; } v;
    v.f = f;
    unsigned int x = v.i;
    unsigned int r = x + 0x7fffu + ((x >> 16) & 1u);  // RNE
    return (unsigned short)(r >> 16);
}
static __device__ __forceinline__ short8 pack_bf16x8(floatx4 a, floatx4 b) {
    short8 r;
    r[0] = (short)f32_to_bf16(a[0]); r[1] = (short)f32_to_bf16(a[1]);
    r[2] = (short)f32_to_bf16(a[2]); r[3] = (short)f32_to_bf16(a[3]);
    r[4] = (short)f32_to_bf16(b[0]); r[5] = (short)f32_to_bf16(b[1]);
    r[6] = (short)f32_to_bf16(b[2]); r[7] = (short)f32_to_bf16(b[3]);
    return r;
}
static __device__ __forceinline__ float fast_tanh(float x) {
    float ax = fabsf(x);
    float e = __expf(2.0f * ax);                       // v_exp_f32 path
    float r = 1.0f - 2.0f * __builtin_amdgcn_rcpf(e + 1.0f);
    return copysignf(r, x);
}

// ---------------------------------------------------------------------------
// Shared GEMM for Phase A and Phase C.
//   C[m][n] = sum_k W[m][k] * X[n][k]      (both operands K-contiguous)
// Phase A: W=W_i2h (512x256), X=x (131072x256), out = Pre bf16 [t][b][nh]
// Phase C: W=W_h2y (256x512), X=hs (131072x512), out = y  f32  [r][ny]
// Tile: 128(M) x 64(N) x 32(K); 256 threads = 4 waves in 2x2.
// ---------------------------------------------------------------------------
template <int KDIM, bool OUT_PRE>
__global__ __launch_bounds__(256, 4) void gemm_wx(const float* __restrict__ W,
                                                  const float* __restrict__ X,
                                                  void* __restrict__ outp) {
    __shared__ alignas(16) unsigned short Asm[128 * 32];
    __shared__ alignas(16) unsigned short Bsm[64 * 32];
    const int tid = threadIdx.x;
    const int w = tid >> 6, L = tid & 63, q = L >> 4, ln = L & 15;
    const int m0 = blockIdx.y * 128;
    const int n0 = blockIdx.x * 64;
    const int wm = (w >> 1) * 64;
    const int wn = (w & 1) * 32;

    floatx4 acc[4][2];
#pragma unroll
    for (int rt = 0; rt < 4; ++rt)
#pragma unroll
        for (int ct = 0; ct < 2; ++ct) acc[rt][ct] = (floatx4){0.f, 0.f, 0.f, 0.f};

    for (int k0 = 0; k0 < KDIM; k0 += 32) {
        {   // stage A tile (128x32 f32 -> bf16)
            int row = tid >> 1;
            int col0 = (tid & 1) * 16;
            const float* src = W + (size_t)(m0 + row) * KDIM + k0 + col0;
            floatx4 v0 = *(const floatx4*)(src + 0);
            floatx4 v1 = *(const floatx4*)(src + 4);
            floatx4 v2 = *(const floatx4*)(src + 8);
            floatx4 v3 = *(const floatx4*)(src + 12);
            *(short8*)&Asm[row * 32 + col0] = pack_bf16x8(v0, v1);
            *(short8*)&Asm[row * 32 + col0 + 8] = pack_bf16x8(v2, v3);
        }
        {   // stage B tile (64x32)
            int row = tid >> 2;
            int col0 = (tid & 3) * 8;
            const float* src = X + (size_t)(n0 + row) * KDIM + k0 + col0;
            floatx4 v0 = *(const floatx4*)(src);
            floatx4 v1 = *(const floatx4*)(src + 4);
            *(short8*)&Bsm[row * 32 + col0] = pack_bf16x8(v0, v1);
        }
        __syncthreads();
        short8 af[4], bf[2];
#pragma unroll
        for (int rt = 0; rt < 4; ++rt)
            af[rt] = *(const short8*)&Asm[(wm + rt * 16 + ln) * 32 + q * 8];
#pragma unroll
        for (int ct = 0; ct < 2; ++ct)
            bf[ct] = *(const short8*)&Bsm[(wn + ct * 16 + ln) * 32 + q * 8];
#pragma unroll
        for (int rt = 0; rt < 4; ++rt)
#pragma unroll
            for (int ct = 0; ct < 2; ++ct)
                acc[rt][ct] = __builtin_amdgcn_mfma_f32_16x16x32_bf16(
                    af[rt], bf[ct], acc[rt][ct], 0, 0, 0);
        __syncthreads();
    }

#pragma unroll
    for (int rt = 0; rt < 4; ++rt) {
#pragma unroll
        for (int ct = 0; ct < 2; ++ct) {
            const int m = m0 + wm + rt * 16 + q * 4;       // 4 consecutive m
            const int r = n0 + wn + ct * 16 + ln;          // flat col = b*1024+t
            if (OUT_PRE) {
                const int t = r & 1023, b = r >> 10;
                unsigned short* o =
                    (unsigned short*)outp + ((size_t)(t * 128 + b)) * 512 + m;
                ushort4v pk;
                pk[0] = f32_to_bf16(acc[rt][ct][0]);
                pk[1] = f32_to_bf16(acc[rt][ct][1]);
                pk[2] = f32_to_bf16(acc[rt][ct][2]);
                pk[3] = f32_to_bf16(acc[rt][ct][3]);
                *(ushort4v*)o = pk;
            } else {
                float* o = (float*)outp + (size_t)r * NY + m;
                *(floatx4*)o = acc[rt][ct];
            }
        }
    }
}

// ---------------------------------------------------------------------------
// Init: scatter h0 (f32 [b][nh]) into B-fragment-layout exchange buffers,
// parity 1 (read at t=0). Layout per buf (4096 ushorts):
//   elem = kt*512 + chain*32 + qq*8 + j   where nh_local = kt*32 + qq*8 + j
// ---------------------------------------------------------------------------
__global__ void init_h(const float* __restrict__ h0,
                       unsigned short* __restrict__ bufs) {
    int idx = blockIdx.x * 256 + threadIdx.x;
    if (idx >= B_DIM * NH) return;
    int b = idx >> 9, nh = idx & 511;
    int s = b >> 4, c = b & 15;
    int half = nh >> 8;
    int wg = half * 8 + s;
    int nl = nh & 255;
    int kt = nl >> 5, kk = nl & 31, qq = kk >> 3, j = kk & 7;
    size_t off = ((size_t)(wg * 2 + 1)) * 4096 + kt * 512 + c * 32 + qq * 8 + j;
    bufs[off] = f32_to_bf16(h0[(size_t)b * NH + nh]);
}

// ---------------------------------------------------------------------------
// Phase B: the recurrence. 16 WGs x 512 threads.
//   wg = half*8 + s ; set s owns chains b = s*16..s*16+15 ; half owns rows
//   [half*256, half*256+256). Weights for the 256x512 slice live in VGPRs as
//   pre-packed A-fragments (128 regs/wave). Partner halves exchanged via
//   global bufs (t-parity double buffered) + monotone agent-scope flags.
// ---------------------------------------------------------------------------
__global__ __launch_bounds__(512, 2) void rnn_step(
    const float* __restrict__ Wh, const unsigned short* __restrict__ Pre,
    float* __restrict__ hs_out, unsigned short* __restrict__ bufs,
    int* __restrict__ flags) {
    const int wg = blockIdx.x;
    const int s = wg & 7, half = wg >> 3;
    const int partner = wg ^ 8;
    const int tid = threadIdx.x;
    const int w = tid >> 6, L = tid & 63, q = L >> 4, ln = L & 15;
    const int b = s * 16 + ln;  // this lane's chain (MFMA N-col)

    __shared__ alignas(16) unsigned short Hown[4096];  // 8 KB own-half h (frag layout)

    // ---- preload Wh slice into registers as A-fragments --------------------
    // rows n = half*256 + w*32 + rt*16 + (L&15); k = kt*32 + q*8 + j
    short8 Wown[2][8];   // k-tiles of MY half  (global kt = half*8 + lt)
    short8 Wpart[2][8];  // k-tiles of partner half
#pragma unroll
    for (int rt = 0; rt < 2; ++rt) {
        const int n = half * 256 + w * 32 + rt * 16 + ln;
        const float* rowp = Wh + (size_t)n * NH;
#pragma unroll
        for (int lt = 0; lt < 8; ++lt) {
            {
                const float* src = rowp + (half * 8 + lt) * 32 + q * 8;
                floatx4 a0 = *(const floatx4*)(src);
                floatx4 a1 = *(const floatx4*)(src + 4);
                Wown[rt][lt] = pack_bf16x8(a0, a1);
            }
            {
                const float* src = rowp + ((half ^ 1) * 8 + lt) * 32 + q * 8;
                floatx4 a0 = *(const floatx4*)(src);
                floatx4 a1 = *(const floatx4*)(src + 4);
                Wpart[rt][lt] = pack_bf16x8(a0, a1);
            }
        }
    }

    unsigned short* myb0 = bufs + ((size_t)(wg * 2 + 0)) * 4096;
    unsigned short* myb1 = bufs + ((size_t)(wg * 2 + 1)) * 4096;
    const unsigned short* pb0 = bufs + ((size_t)(partner * 2 + 0)) * 4096;
    const unsigned short* pb1 = bufs + ((size_t)(partner * 2 + 1)) * 4096;

    int alive = 1;  // poll bail-out so a logic bug can't hang the bench

    for (int t = 0; t < T_DIM; ++t) {
        // ---- Pre (acc init), issued early ---------------------------------
        floatx4 acc[2];
#pragma unroll
        for (int rt = 0; rt < 2; ++rt) {
            const int nh0 = half * 256 + w * 32 + rt * 16 + q * 4;
            const unsigned short* pp =
                Pre + ((size_t)(t * 128 + b)) * 512 + nh0;
            ushort4v pv = *(const ushort4v*)pp;
            floatx4 a;
            a[0] = bf16_to_f32(pv[0]); a[1] = bf16_to_f32(pv[1]);
            a[2] = bf16_to_f32(pv[2]); a[3] = bf16_to_f32(pv[3]);
            acc[rt] = a;
        }

        short8 bo[8], bp[8];
        if (t == 0) {
            // init data (parity 1) for both halves; ordered by kernel launch
            const unsigned short* ob = myb1;
#pragma unroll
            for (int lt = 0; lt < 8; ++lt)
                bp[lt] = *(const short8*)(pb1 + lt * 512 + ln * 32 + q * 8);
#pragma unroll
            for (int lt = 0; lt < 8; ++lt)
                bo[lt] = *(const short8*)(ob + lt * 512 + ln * 32 + q * 8);
        } else {
            if (tid == 0 && alive) {
                int spins = 0;
                while (__hip_atomic_load(flags + partner, __ATOMIC_ACQUIRE,
                                         __HIP_MEMORY_SCOPE_AGENT) < t) {
                    __builtin_amdgcn_s_sleep(2);
                    if (++spins > (1 << 22)) { alive = 0; break; }
                }
            }
            __syncthreads();
            const unsigned short* pb = ((t - 1) & 1) ? pb1 : pb0;
#pragma unroll
            for (int lt = 0; lt < 8; ++lt)  // partner frags: global (issue 1st)
                bp[lt] = *(const short8*)(pb + lt * 512 + ln * 32 + q * 8);
#pragma unroll
            for (int lt = 0; lt < 8; ++lt)  // own frags: LDS
                bo[lt] = *(const short8*)(Hown + lt * 512 + ln * 32 + q * 8);
        }

        // ---- MFMA: own half first (hides partner load latency) ------------
#pragma unroll
        for (int lt = 0; lt < 8; ++lt) {
            acc[0] = __builtin_amdgcn_mfma_f32_16x16x32_bf16(Wown[0][lt], bo[lt],
                                                             acc[0], 0, 0, 0);
            acc[1] = __builtin_amdgcn_mfma_f32_16x16x32_bf16(Wown[1][lt], bo[lt],
                                                             acc[1], 0, 0, 0);
        }
#pragma unroll
        for (int lt = 0; lt < 8; ++lt) {
            acc[0] = __builtin_amdgcn_mfma_f32_16x16x32_bf16(Wpart[0][lt], bp[lt],
                                                             acc[0], 0, 0, 0);
            acc[1] = __builtin_amdgcn_mfma_f32_16x16x32_bf16(Wpart[1][lt], bp[lt],
                                                             acc[1], 0, 0, 0);
        }

        __syncthreads();  // all Hown readers done before overwrite

        // ---- tanh + stores -------------------------------------------------
        unsigned short* gb = (t & 1) ? myb1 : myb0;
#pragma unroll
        for (int rt = 0; rt < 2; ++rt) {
            floatx4 hv;
            hv[0] = fast_tanh(acc[rt][0]);
            hv[1] = fast_tanh(acc[rt][1]);
            hv[2] = fast_tanh(acc[rt][2]);
            hv[3] = fast_tanh(acc[rt][3]);
            const int nh0 = half * 256 + w * 32 + rt * 16 + q * 4;
            float* hp = hs_out + ((size_t)b * 1024 + t) * 512 + nh0;
            *(floatx4*)hp = hv;  // fp32 hs output
            ushort4v pk;
            pk[0] = f32_to_bf16(hv[0]); pk[1] = f32_to_bf16(hv[1]);
            pk[2] = f32_to_bf16(hv[2]); pk[3] = f32_to_bf16(hv[3]);
            // frag layout: kt=w, kk=rt*16+q*4+i -> qq=rt*2+(q>>1), j0=(q&1)*4
            const int off = w * 512 + ln * 32 + (rt * 2 + (q >> 1)) * 8 + (q & 1) * 4;
            *(ushort4v*)(Hown + off) = pk;
            *(ushort4v*)(gb + off) = pk;
        }

        __syncthreads();  // drains vmcnt before barrier -> stores complete
        if (tid == 0) {
            __threadfence();
            __hip_atomic_store(flags + wg, t + 1, __ATOMIC_RELEASE,
                               __HIP_MEMORY_SCOPE_AGENT);
        }
    }
}

// ---------------------------------------------------------------------------
extern "C" void kernel_launch(void* const* d_in, const int* in_sizes, int n_in,
                              void* d_out, int out_size, void* d_ws,
                              size_t ws_size, hipStream_t stream) {
    const float* x  = (const float*)d_in[0];
    const float* h0 = (const float*)d_in[1];
    const float* Wi = (const float*)d_in[2];
    const float* Wh = (const float*)d_in[3];
    const float* Wy = (const float*)d_in[4];
    float* out = (float*)d_out;

    int* flags = (int*)d_ws;
    unsigned short* bufs = (unsigned short*)((char*)d_ws + 1024);
    unsigned short* Pre = (unsigned short*)d_out;  // bf16 Pre in y-region
    float* hs = out + Y_ELEMS;

    (void)hipMemsetAsync(d_ws, 0, 1024, stream);  // zero the flags

    // Phase A: Pre[t][b][nh] = bf16( x @ Wi^T )
    gemm_wx<NX, true><<<dim3(B_DIM * T_DIM / 64, NH / 128), 256, 0, stream>>>(
        Wi, x, (void*)Pre);

    // scatter initial h into exchange buffers (parity 1)
    init_h<<<dim3(B_DIM * NH / 256), 256, 0, stream>>>(h0, bufs);

    // Phase B: recurrence -> hs (fp32)
    rnn_step<<<dim3(16), 512, 0, stream>>>(Wh, Pre, hs, bufs, flags);

    // Phase C: y = hs @ Wy^T (overwrites Pre region with final y)
    gemm_wx<NH, false><<<dim3(B_DIM * T_DIM / 64, NY / 128), 256, 0, stream>>>(
        Wy, hs, (void*)out);
}